// Round 4
// baseline (459.995 us; speedup 1.0000x reference)
//
#include <hip/hip_runtime.h>

#define NROWS 32768
#define FDIM  2048
#define CDIM  64
#define BM    64
#define BK    64
#define NCH   (FDIM / BK)    // 32 chunks of 64 k
#define CHB   16384          // bytes per packed chunk: bh 8 KiB + bl 8 KiB
#define EPS_R 1e-6f
#define WSCALE 1024.0f
#define DESCALE (2.0f / WSCALE)

typedef __attribute__((ext_vector_type(8))) _Float16 half8;
typedef __attribute__((ext_vector_type(4))) float    f32x4;

__device__ __forceinline__ unsigned packh(_Float16 a, _Float16 b) {
    return (unsigned)__builtin_bit_cast(unsigned short, a) |
           ((unsigned)__builtin_bit_cast(unsigned short, b) << 16);
}

__device__ __forceinline__ void split2(float a, float b, unsigned& hi, unsigned& lo) {
    _Float16 ha = (_Float16)a, hb = (_Float16)b;
    _Float16 la = (_Float16)(a - (float)ha), lb = (_Float16)(b - (float)hb);
    hi = packh(ha, hb);
    lo = packh(la, lb);
}

__device__ __forceinline__ void split8(const float4& X0, const float4& X1,
                                       const float4& R0, const float4& R1,
                                       half8& AH, half8& AL, float& p) {
    const float v_[8] = {X0.x, X0.y, X0.z, X0.w, X1.x, X1.y, X1.z, X1.w};
    const float w_[8] = {R0.x, R0.y, R0.z, R0.w, R1.x, R1.y, R1.z, R1.w};
#pragma unroll
    for (int j = 0; j < 8; j++) {
        const float v = v_[j];
        const _Float16 h = (_Float16)v;
        AH[j] = h;
        AL[j] = (_Float16)(v - (float)h);
        p += w_[j] * v * v;
    }
}

// ---- prep: pack B image linearly: [32 chunks][bh 64 classes x 128 B | bl same]
//      (B is consumed straight from L2 by the main kernel; no LDS, no swizzle) ----
__global__ __launch_bounds__(256) void gmlvq_prep(
    const float* __restrict__ W, const float* __restrict__ r,
    unsigned char* __restrict__ Bsw,
    float* __restrict__ wsq, float* __restrict__ rc_out) {
    const int c = blockIdx.x;
    const int tid = threadIdx.x;
    const int f0 = tid * 8;                       // 256*8 = 2048 exactly

    const float* Wp = W + (size_t)c * FDIM + f0;
    float4 w0 = *(const float4*)Wp;
    float4 w1 = *(const float4*)(Wp + 4);
    float4 r0 = *(const float4*)(r + f0);
    float4 r1 = *(const float4*)(r + f0 + 4);
    r0.x = fmaxf(r0.x, EPS_R); r0.y = fmaxf(r0.y, EPS_R);
    r0.z = fmaxf(r0.z, EPS_R); r0.w = fmaxf(r0.w, EPS_R);
    r1.x = fmaxf(r1.x, EPS_R); r1.y = fmaxf(r1.y, EPS_R);
    r1.z = fmaxf(r1.z, EPS_R); r1.w = fmaxf(r1.w, EPS_R);

    if (c == 0) {
        *(float4*)(rc_out + f0) = r0;
        *(float4*)(rc_out + f0 + 4) = r1;
    }

    float rw0 = r0.x * w0.x, rw1 = r0.y * w0.y, rw2 = r0.z * w0.z, rw3 = r0.w * w0.w;
    float rw4 = r1.x * w1.x, rw5 = r1.y * w1.y, rw6 = r1.z * w1.z, rw7 = r1.w * w1.w;

    float part = rw0 * w0.x + rw1 * w0.y + rw2 * w0.z + rw3 * w0.w
               + rw4 * w1.x + rw5 * w1.y + rw6 * w1.z + rw7 * w1.w;

    unsigned h01, l01, h23, l23, h45, l45, h67, l67;
    split2(rw0 * WSCALE, rw1 * WSCALE, h01, l01);
    split2(rw2 * WSCALE, rw3 * WSCALE, h23, l23);
    split2(rw4 * WSCALE, rw5 * WSCALE, h45, l45);
    split2(rw6 * WSCALE, rw7 * WSCALE, h67, l67);

    // linear destination: chunk ch, class-row c, halves k6..k6+7
    const int ch = f0 >> 6;
    const int k6 = f0 & 63;
    unsigned char* dst = Bsw + (size_t)ch * CHB + c * 128 + k6 * 2;
    *(uint4*)dst = make_uint4(h01, h23, h45, h67);          // bh region
    *(uint4*)(dst + 8192) = make_uint4(l01, l23, l45, l67); // bl region

#pragma unroll
    for (int m = 32; m; m >>= 1) part += __shfl_xor(part, m);
    __shared__ float red[4];
    if ((tid & 63) == 0) red[tid >> 6] = part;
    __syncthreads();
    if (tid == 0) wsq[c] = (red[0] + red[1]) + (red[2] + red[3]);
}

// ---- main: barrier-free K-loop. A: global->reg (1-deep prefetch).
//      B: per-lane MFMA fragments loaded straight from the L2-resident image. ----
__global__ __launch_bounds__(256, 2) void gmlvq_main(
    const float* __restrict__ X, const float* __restrict__ rc,
    const unsigned char* __restrict__ Bsw,
    const float* __restrict__ wsq_g,
    float* __restrict__ dists, float* __restrict__ preds) {

    __shared__ float lds_xsq[BM];
    __shared__ float lds_wsq[CDIM];

    const int tid  = threadIdx.x;
    const int wave = tid >> 6;
    const int lane = tid & 63;
    const int quad = lane >> 4;
    const int l15  = lane & 15;
    const int row_base = blockIdx.x * BM;

    if (tid < CDIM) lds_wsq[tid] = wsq_g[tid];

    const float* Ap = X + (size_t)(row_base + wave * 16 + l15) * FDIM + quad * 8;
    const float* Rp = rc + quad * 8;
    // per-lane B fragment base within a chunk: class-row l15 (+n*16), k-bytes quad*16
    const unsigned char* Bq = Bsw + (size_t)(l15 * 128 + quad * 16);

    // prologue: A/rc chunk 0 -> regs
    float4 x0 = *(const float4*)(Ap);
    float4 x1 = *(const float4*)(Ap + 4);
    float4 x2 = *(const float4*)(Ap + 32);
    float4 x3 = *(const float4*)(Ap + 36);
    float4 r0 = *(const float4*)(Rp);
    float4 r1 = *(const float4*)(Rp + 4);
    float4 r2 = *(const float4*)(Rp + 32);
    float4 r3 = *(const float4*)(Rp + 36);

    float p = 0.f;     // per-lane x_sq partial
    f32x4 acc[4];
#pragma unroll
    for (int n = 0; n < 4; n++) acc[n] = (f32x4){0.f, 0.f, 0.f, 0.f};

    for (int c = 0; c < NCH; c++) {
        const unsigned char* Bc = Bq + (size_t)c * CHB;

        // B fragments for this chunk (16 x 16B from L2; issued up front)
        half8 bh[4][2], bl[4][2];
#pragma unroll
        for (int n = 0; n < 4; n++) {
            bh[n][0] = *(const half8*)(Bc + n * 2048);
            bh[n][1] = *(const half8*)(Bc + n * 2048 + 64);
            bl[n][0] = *(const half8*)(Bc + n * 2048 + 8192);
            bl[n][1] = *(const half8*)(Bc + n * 2048 + 8192 + 64);
        }

        // next A/rc chunk -> regs (wrap at end harmless)
        const int kn = ((c + 1) & (NCH - 1)) * BK;
        const float4 xn0 = *(const float4*)(Ap + kn);
        const float4 xn1 = *(const float4*)(Ap + kn + 4);
        const float4 xn2 = *(const float4*)(Ap + kn + 32);
        const float4 xn3 = *(const float4*)(Ap + kn + 36);
        const float4 rn0 = *(const float4*)(Rp + kn);
        const float4 rn1 = *(const float4*)(Rp + kn + 4);
        const float4 rn2 = *(const float4*)(Rp + kn + 32);
        const float4 rn3 = *(const float4*)(Rp + kn + 36);

        // split current A regs into fp16 hi/lo frags + r*x^2 partial
        half8 ah0, al0, ah1, al1;
        split8(x0, x1, r0, r1, ah0, al0, p);     // k-slice 0 (halves 0..31)
        split8(x2, x3, r2, r3, ah1, al1, p);     // k-slice 1 (halves 32..63)

#pragma unroll
        for (int n = 0; n < 4; n++) {
            acc[n] = __builtin_amdgcn_mfma_f32_16x16x32_f16(ah0, bh[n][0], acc[n], 0, 0, 0);
            acc[n] = __builtin_amdgcn_mfma_f32_16x16x32_f16(ah0, bl[n][0], acc[n], 0, 0, 0);
            acc[n] = __builtin_amdgcn_mfma_f32_16x16x32_f16(al0, bh[n][0], acc[n], 0, 0, 0);
            acc[n] = __builtin_amdgcn_mfma_f32_16x16x32_f16(ah1, bh[n][1], acc[n], 0, 0, 0);
            acc[n] = __builtin_amdgcn_mfma_f32_16x16x32_f16(ah1, bl[n][1], acc[n], 0, 0, 0);
            acc[n] = __builtin_amdgcn_mfma_f32_16x16x32_f16(al1, bh[n][1], acc[n], 0, 0, 0);
        }

        x0 = xn0; x1 = xn1; x2 = xn2; x3 = xn3;
        r0 = rn0; r1 = rn1; r2 = rn2; r3 = rn3;
    }

    // x_sq: reduce across the 4 quads holding the same row
    p += __shfl_xor(p, 16);
    p += __shfl_xor(p, 32);
    if (quad == 0) lds_xsq[wave * 16 + l15] = p;
    __syncthreads();

    // epilogue: d = x_sq + w_sq - 2*cross ; C/D layout: col=lane&15, row=quad*4+reg
    float dd[4][4];
#pragma unroll
    for (int n = 0; n < 4; n++) {
#pragma unroll
        for (int rr = 0; rr < 4; rr++) {
            const int m = wave * 16 + quad * 4 + rr;
            const int cc = n * 16 + l15;
            const float d = lds_xsq[m] + lds_wsq[cc] - acc[n][rr] * DESCALE;
            dd[n][rr] = d;
            dists[(size_t)(row_base + m) * CDIM + cc] = d;
        }
    }

    // argmin over 64 classes per row (lowest-index tie-break)
#pragma unroll
    for (int rr = 0; rr < 4; rr++) {
        float bv = dd[0][rr];
        int   bi = l15;
#pragma unroll
        for (int n = 1; n < 4; n++) {
            const float v = dd[n][rr];
            const int  ci = n * 16 + l15;
            if (v < bv || (v == bv && ci < bi)) { bv = v; bi = ci; }
        }
#pragma unroll
        for (int mask = 1; mask < 16; mask <<= 1) {
            const float ov = __shfl_xor(bv, mask);
            const int   oi = __shfl_xor(bi, mask);
            if (ov < bv || (ov == bv && oi < bi)) { bv = ov; bi = oi; }
        }
        if (l15 == 0) {
            const int m = wave * 16 + quad * 4 + rr;
            preds[row_base + m] = (float)bi;
        }
    }
}

extern "C" void kernel_launch(void* const* d_in, const int* in_sizes, int n_in,
                              void* d_out, int out_size, void* d_ws, size_t ws_size,
                              hipStream_t stream) {
    const float* X = (const float*)d_in[0];
    const float* W = (const float*)d_in[1];
    const float* r = (const float*)d_in[2];
    float* dists = (float*)d_out;
    float* preds = dists + (size_t)NROWS * CDIM;

    unsigned char* Bsw = (unsigned char*)d_ws;                  // 512 KiB packed B image
    float* wsq   = (float*)(Bsw + (size_t)NCH * CHB);           // 256 B
    float* rc_ws = wsq + CDIM;                                  // 8 KiB

    gmlvq_prep<<<dim3(CDIM), dim3(256), 0, stream>>>(W, r, Bsw, wsq, rc_ws);
    gmlvq_main<<<dim3(NROWS / BM), dim3(256), 0, stream>>>(X, rc_ws, Bsw, wsq, dists, preds);
}

// Round 5
// 397.463 us; speedup vs baseline: 1.1573x; 1.1573x over previous
//
#include <hip/hip_runtime.h>

#define NROWS 32768
#define FDIM  2048
#define CDIM  64
#define BM    64
#define BK    64
#define NCH   (FDIM / BK)    // 32 chunks of 64 k
#define NPER  (NCH / 2)      // 16 barrier periods, 2 chunks each
#define CHB   16384          // bytes per staged chunk image: bh 8 KiB + bl 8 KiB
#define EPS_R 1e-6f
#define WSCALE 1024.0f
#define DESCALE (2.0f / WSCALE)

typedef __attribute__((ext_vector_type(8))) _Float16 half8;
typedef __attribute__((ext_vector_type(4))) float    f32x4;

__device__ __forceinline__ unsigned packh(_Float16 a, _Float16 b) {
    return (unsigned)__builtin_bit_cast(unsigned short, a) |
           ((unsigned)__builtin_bit_cast(unsigned short, b) << 16);
}

__device__ __forceinline__ void split2(float a, float b, unsigned& hi, unsigned& lo) {
    _Float16 ha = (_Float16)a, hb = (_Float16)b;
    _Float16 la = (_Float16)(a - (float)ha), lb = (_Float16)(b - (float)hb);
    hi = packh(ha, hb);
    lo = packh(la, lb);
}

// async 16B/lane global->LDS DMA (dest = lds_base + lane*16, src per-lane)
__device__ __forceinline__ void async16(const void* g, void* l) {
    __builtin_amdgcn_global_load_lds(
        (const __attribute__((address_space(1))) void*)g,
        (__attribute__((address_space(3))) void*)l, 16, 0, 0);
}

__device__ __forceinline__ void split8(const float4& X0, const float4& X1,
                                       const float4& R0, const float4& R1,
                                       half8& AH, half8& AL, float& p) {
    const float v_[8] = {X0.x, X0.y, X0.z, X0.w, X1.x, X1.y, X1.z, X1.w};
    const float w_[8] = {R0.x, R0.y, R0.z, R0.w, R1.x, R1.y, R1.z, R1.w};
#pragma unroll
    for (int j = 0; j < 8; j++) {
        const float v = v_[j];
        const _Float16 h = (_Float16)v;
        AH[j] = h;
        AL[j] = (_Float16)(v - (float)h);
        p += w_[j] * v * v;
    }
}

// ---- prep: build pre-swizzled B image: [32 chunks][bh 64x128B | bl 64x128B],
//      byte-in-row ^= (class&7)<<4  (conflict-free-parity reads, linear DMA) ----
__global__ __launch_bounds__(256) void gmlvq_prep(
    const float* __restrict__ W, const float* __restrict__ r,
    unsigned char* __restrict__ Bsw,
    float* __restrict__ wsq, float* __restrict__ rc_out) {
    const int c = blockIdx.x;
    const int tid = threadIdx.x;
    const int f0 = tid * 8;                       // 256*8 = 2048 exactly

    const float* Wp = W + (size_t)c * FDIM + f0;
    float4 w0 = *(const float4*)Wp;
    float4 w1 = *(const float4*)(Wp + 4);
    float4 r0 = *(const float4*)(r + f0);
    float4 r1 = *(const float4*)(r + f0 + 4);
    r0.x = fmaxf(r0.x, EPS_R); r0.y = fmaxf(r0.y, EPS_R);
    r0.z = fmaxf(r0.z, EPS_R); r0.w = fmaxf(r0.w, EPS_R);
    r1.x = fmaxf(r1.x, EPS_R); r1.y = fmaxf(r1.y, EPS_R);
    r1.z = fmaxf(r1.z, EPS_R); r1.w = fmaxf(r1.w, EPS_R);

    if (c == 0) {
        *(float4*)(rc_out + f0) = r0;
        *(float4*)(rc_out + f0 + 4) = r1;
    }

    float rw0 = r0.x * w0.x, rw1 = r0.y * w0.y, rw2 = r0.z * w0.z, rw3 = r0.w * w0.w;
    float rw4 = r1.x * w1.x, rw5 = r1.y * w1.y, rw6 = r1.z * w1.z, rw7 = r1.w * w1.w;

    float part = rw0 * w0.x + rw1 * w0.y + rw2 * w0.z + rw3 * w0.w
               + rw4 * w1.x + rw5 * w1.y + rw6 * w1.z + rw7 * w1.w;

    unsigned h01, l01, h23, l23, h45, l45, h67, l67;
    split2(rw0 * WSCALE, rw1 * WSCALE, h01, l01);
    split2(rw2 * WSCALE, rw3 * WSCALE, h23, l23);
    split2(rw4 * WSCALE, rw5 * WSCALE, h45, l45);
    split2(rw6 * WSCALE, rw7 * WSCALE, h67, l67);

    // swizzled destination: chunk ch, class-row c, 16B slot for halves k6..k6+7
    const int ch = f0 >> 6;
    const int k6 = f0 & 63;
    const int rowoff = (k6 * 2) ^ ((c & 7) << 4);
    unsigned char* dst = Bsw + (size_t)ch * CHB + c * 128 + rowoff;
    *(uint4*)dst = make_uint4(h01, h23, h45, h67);          // bh region
    *(uint4*)(dst + 8192) = make_uint4(l01, l23, l45, l67); // bl region

#pragma unroll
    for (int m = 32; m; m >>= 1) part += __shfl_xor(part, m);
    __shared__ float red[4];
    if ((tid & 63) == 0) red[tid >> 6] = part;
    __syncthreads();
    if (tid == 0) wsq[c] = (red[0] + red[1]) + (red[2] + red[3]);
}

// ---- main: 2 chunks per barrier period (16 drains instead of 32);
//      A: global->reg 2-set prefetch one period deep; B: global_load_lds 4-buf ----
__global__ __launch_bounds__(256, 2) void gmlvq_main(
    const float* __restrict__ X, const float* __restrict__ rc,
    const unsigned char* __restrict__ Bsw,
    const float* __restrict__ wsq_g,
    float* __restrict__ dists, float* __restrict__ preds) {

    __shared__ __align__(16) unsigned char lds_b[2][2][CHB];   // [period parity][chunk in period]
    __shared__ float lds_xsq[BM];
    __shared__ float lds_wsq[CDIM];

    const int tid  = threadIdx.x;
    const int wave = tid >> 6;
    const int lane = tid & 63;
    const int quad = lane >> 4;
    const int l15  = lane & 15;
    const int row_base = blockIdx.x * BM;
    const int wu = __builtin_amdgcn_readfirstlane(wave);   // uniform wave id

    if (tid < CDIM) lds_wsq[tid] = wsq_g[tid];

    const float* Ap = X + (size_t)(row_base + wave * 16 + l15) * FDIM + quad * 8;
    const float* Rp = rc + quad * 8;

    // swizzled column base for LDS fragment reads (bits 4-6); ks=1 is ^64
    const int col0 = ((quad ^ (l15 & 7)) << 4);

    // prologue: DMA chunks 0,1 -> buf[0][0..1]; A/rc chunks 0,1 -> regs
    {
        const unsigned char* s0p = Bsw + (size_t)0 * CHB + wu * 4096 + lane * 16;
        const unsigned char* s1p = Bsw + (size_t)1 * CHB + wu * 4096 + lane * 16;
        unsigned char* d0p = &lds_b[0][0][wu * 4096];
        unsigned char* d1p = &lds_b[0][1][wu * 4096];
#pragma unroll
        for (int j = 0; j < 4; j++) async16(s0p + j * 1024, d0p + j * 1024);
#pragma unroll
        for (int j = 0; j < 4; j++) async16(s1p + j * 1024, d1p + j * 1024);
    }
    float4 x0 = *(const float4*)(Ap);
    float4 x1 = *(const float4*)(Ap + 4);
    float4 x2 = *(const float4*)(Ap + 32);
    float4 x3 = *(const float4*)(Ap + 36);
    float4 r0 = *(const float4*)(Rp);
    float4 r1 = *(const float4*)(Rp + 4);
    float4 r2 = *(const float4*)(Rp + 32);
    float4 r3 = *(const float4*)(Rp + 36);
    float4 y0 = *(const float4*)(Ap + BK);
    float4 y1 = *(const float4*)(Ap + BK + 4);
    float4 y2 = *(const float4*)(Ap + BK + 32);
    float4 y3 = *(const float4*)(Ap + BK + 36);
    float4 s0 = *(const float4*)(Rp + BK);
    float4 s1 = *(const float4*)(Rp + BK + 4);
    float4 s2 = *(const float4*)(Rp + BK + 32);
    float4 s3 = *(const float4*)(Rp + BK + 36);

    float p = 0.f;     // per-lane x_sq partial
    f32x4 acc[4];
#pragma unroll
    for (int n = 0; n < 4; n++) acc[n] = (f32x4){0.f, 0.f, 0.f, 0.f};

#pragma unroll 2
    for (int per = 0; per < NPER; per++) {
        __syncthreads();                 // this period's buffers landed
        const int cur = per & 1;

        // stage next period's two chunks into buf[cur^1][0..1]
        {
            const int c2 = (2 * per + 2) & (NCH - 1);    // ring; wrap harmless
            const int c3 = (2 * per + 3) & (NCH - 1);
            const unsigned char* s2p = Bsw + (size_t)c2 * CHB + wu * 4096 + lane * 16;
            const unsigned char* s3p = Bsw + (size_t)c3 * CHB + wu * 4096 + lane * 16;
            unsigned char* d2p = &lds_b[cur ^ 1][0][wu * 4096];
            unsigned char* d3p = &lds_b[cur ^ 1][1][wu * 4096];
#pragma unroll
            for (int j = 0; j < 4; j++) async16(s2p + j * 1024, d2p + j * 1024);
#pragma unroll
            for (int j = 0; j < 4; j++) async16(s3p + j * 1024, d3p + j * 1024);
        }

        // ---- chunk 2*per (x-set) vs buf[cur][0]
        {
            half8 ah0, al0, ah1, al1;
            split8(x0, x1, r0, r1, ah0, al0, p);
            split8(x2, x3, r2, r3, ah1, al1, p);

            // reload x-set with chunk 2*per+2 (consumed next period)
            const int kn = (2 * per + 2) * BK & (FDIM - 1);
            x0 = *(const float4*)(Ap + kn);
            x1 = *(const float4*)(Ap + kn + 4);
            x2 = *(const float4*)(Ap + kn + 32);
            x3 = *(const float4*)(Ap + kn + 36);
            r0 = *(const float4*)(Rp + kn);
            r1 = *(const float4*)(Rp + kn + 4);
            r2 = *(const float4*)(Rp + kn + 32);
            r3 = *(const float4*)(Rp + kn + 36);

            const unsigned char* Lb = lds_b[cur][0];
#pragma unroll
            for (int n = 0; n < 4; n++) {
                const int o = ((n * 16 + l15) << 7) + col0;
                const half8 bh0 = *(const half8*)(Lb + o);
                const half8 bh1 = *(const half8*)(Lb + (o ^ 64));
                const half8 bl0 = *(const half8*)(Lb + 8192 + o);
                const half8 bl1 = *(const half8*)(Lb + 8192 + (o ^ 64));
                acc[n] = __builtin_amdgcn_mfma_f32_16x16x32_f16(ah0, bh0, acc[n], 0, 0, 0);
                acc[n] = __builtin_amdgcn_mfma_f32_16x16x32_f16(ah0, bl0, acc[n], 0, 0, 0);
                acc[n] = __builtin_amdgcn_mfma_f32_16x16x32_f16(al0, bh0, acc[n], 0, 0, 0);
                acc[n] = __builtin_amdgcn_mfma_f32_16x16x32_f16(ah1, bh1, acc[n], 0, 0, 0);
                acc[n] = __builtin_amdgcn_mfma_f32_16x16x32_f16(ah1, bl1, acc[n], 0, 0, 0);
                acc[n] = __builtin_amdgcn_mfma_f32_16x16x32_f16(al1, bh1, acc[n], 0, 0, 0);
            }
        }

        // ---- chunk 2*per+1 (y-set) vs buf[cur][1]
        {
            half8 ah0, al0, ah1, al1;
            split8(y0, y1, s0, s1, ah0, al0, p);
            split8(y2, y3, s2, s3, ah1, al1, p);

            // reload y-set with chunk 2*per+3 (consumed next period)
            const int kn = (2 * per + 3) * BK & (FDIM - 1);
            y0 = *(const float4*)(Ap + kn);
            y1 = *(const float4*)(Ap + kn + 4);
            y2 = *(const float4*)(Ap + kn + 32);
            y3 = *(const float4*)(Ap + kn + 36);
            s0 = *(const float4*)(Rp + kn);
            s1 = *(const float4*)(Rp + kn + 4);
            s2 = *(const float4*)(Rp + kn + 32);
            s3 = *(const float4*)(Rp + kn + 36);

            const unsigned char* Lb = lds_b[cur][1];
#pragma unroll
            for (int n = 0; n < 4; n++) {
                const int o = ((n * 16 + l15) << 7) + col0;
                const half8 bh0 = *(const half8*)(Lb + o);
                const half8 bh1 = *(const half8*)(Lb + (o ^ 64));
                const half8 bl0 = *(const half8*)(Lb + 8192 + o);
                const half8 bl1 = *(const half8*)(Lb + 8192 + (o ^ 64));
                acc[n] = __builtin_amdgcn_mfma_f32_16x16x32_f16(ah0, bh0, acc[n], 0, 0, 0);
                acc[n] = __builtin_amdgcn_mfma_f32_16x16x32_f16(ah0, bl0, acc[n], 0, 0, 0);
                acc[n] = __builtin_amdgcn_mfma_f32_16x16x32_f16(al0, bh0, acc[n], 0, 0, 0);
                acc[n] = __builtin_amdgcn_mfma_f32_16x16x32_f16(ah1, bh1, acc[n], 0, 0, 0);
                acc[n] = __builtin_amdgcn_mfma_f32_16x16x32_f16(ah1, bl1, acc[n], 0, 0, 0);
                acc[n] = __builtin_amdgcn_mfma_f32_16x16x32_f16(al1, bh1, acc[n], 0, 0, 0);
            }
        }
    }

    // x_sq: reduce across the 4 quads holding the same row
    p += __shfl_xor(p, 16);
    p += __shfl_xor(p, 32);
    if (quad == 0) lds_xsq[wave * 16 + l15] = p;
    __syncthreads();

    // epilogue: d = x_sq + w_sq - 2*cross ; C/D layout: col=lane&15, row=quad*4+reg
    float dd[4][4];
#pragma unroll
    for (int n = 0; n < 4; n++) {
#pragma unroll
        for (int rr = 0; rr < 4; rr++) {
            const int m = wave * 16 + quad * 4 + rr;
            const int cc = n * 16 + l15;
            const float d = lds_xsq[m] + lds_wsq[cc] - acc[n][rr] * DESCALE;
            dd[n][rr] = d;
            dists[(size_t)(row_base + m) * CDIM + cc] = d;
        }
    }

    // argmin over 64 classes per row (lowest-index tie-break)
#pragma unroll
    for (int rr = 0; rr < 4; rr++) {
        float bv = dd[0][rr];
        int   bi = l15;
#pragma unroll
        for (int n = 1; n < 4; n++) {
            const float v = dd[n][rr];
            const int  ci = n * 16 + l15;
            if (v < bv || (v == bv && ci < bi)) { bv = v; bi = ci; }
        }
#pragma unroll
        for (int mask = 1; mask < 16; mask <<= 1) {
            const float ov = __shfl_xor(bv, mask);
            const int   oi = __shfl_xor(bi, mask);
            if (ov < bv || (ov == bv && oi < bi)) { bv = ov; bi = oi; }
        }
        if (l15 == 0) {
            const int m = wave * 16 + quad * 4 + rr;
            preds[row_base + m] = (float)bi;
        }
    }
}

extern "C" void kernel_launch(void* const* d_in, const int* in_sizes, int n_in,
                              void* d_out, int out_size, void* d_ws, size_t ws_size,
                              hipStream_t stream) {
    const float* X = (const float*)d_in[0];
    const float* W = (const float*)d_in[1];
    const float* r = (const float*)d_in[2];
    float* dists = (float*)d_out;
    float* preds = dists + (size_t)NROWS * CDIM;

    unsigned char* Bsw = (unsigned char*)d_ws;                  // 512 KiB swizzled B image
    float* wsq   = (float*)(Bsw + (size_t)NCH * CHB);           // 256 B
    float* rc_ws = wsq + CDIM;                                  // 8 KiB

    gmlvq_prep<<<dim3(CDIM), dim3(256), 0, stream>>>(W, r, Bsw, wsq, rc_ws);
    gmlvq_main<<<dim3(NROWS / BM), dim3(256), 0, stream>>>(X, rc_ws, Bsw, wsq, dists, preds);
}

// Round 6
// 383.956 us; speedup vs baseline: 1.1980x; 1.0352x over previous
//
#include <hip/hip_runtime.h>

#define NROWS 32768
#define FDIM  2048
#define CDIM  64
#define BM    64
#define BK    64
#define NCH   (FDIM / BK)    // 32 chunks of 64 k
#define CHB   16384          // bytes per staged chunk image: bh 8 KiB + bl 8 KiB
#define EPS_R 1e-6f
#define WSCALE 1024.0f
#define DESCALE (2.0f / WSCALE)

typedef __attribute__((ext_vector_type(8))) _Float16 half8;
typedef __attribute__((ext_vector_type(4))) float    f32x4;

__device__ __forceinline__ unsigned packh(_Float16 a, _Float16 b) {
    return (unsigned)__builtin_bit_cast(unsigned short, a) |
           ((unsigned)__builtin_bit_cast(unsigned short, b) << 16);
}

__device__ __forceinline__ void split2(float a, float b, unsigned& hi, unsigned& lo) {
    _Float16 ha = (_Float16)a, hb = (_Float16)b;
    _Float16 la = (_Float16)(a - (float)ha), lb = (_Float16)(b - (float)hb);
    hi = packh(ha, hb);
    lo = packh(la, lb);
}

// async 16B/lane global->LDS DMA (dest = wave-uniform base + lane*16)
__device__ __forceinline__ void async16(const void* g, void* l) {
    __builtin_amdgcn_global_load_lds(
        (const __attribute__((address_space(1))) void*)g,
        (__attribute__((address_space(3))) void*)l, 16, 0, 0);
}

__device__ __forceinline__ void split8(const float4& X0, const float4& X1,
                                       const float4& R0, const float4& R1,
                                       half8& AH, half8& AL, float& p) {
    const float v_[8] = {X0.x, X0.y, X0.z, X0.w, X1.x, X1.y, X1.z, X1.w};
    const float w_[8] = {R0.x, R0.y, R0.z, R0.w, R1.x, R1.y, R1.z, R1.w};
#pragma unroll
    for (int j = 0; j < 8; j++) {
        const float v = v_[j];
        const _Float16 h = (_Float16)v;
        AH[j] = h;
        AL[j] = (_Float16)(v - (float)h);
        p += w_[j] * v * v;
    }
}

// ---- prep: build pre-swizzled B image: [32 chunks][bh 64x128B | bl 64x128B],
//      byte-in-row ^= (class&7)<<4  (conflict-free-parity reads, linear DMA) ----
__global__ __launch_bounds__(256) void gmlvq_prep(
    const float* __restrict__ W, const float* __restrict__ r,
    unsigned char* __restrict__ Bsw,
    float* __restrict__ wsq, float* __restrict__ rc_out) {
    const int c = blockIdx.x;
    const int tid = threadIdx.x;
    const int f0 = tid * 8;                       // 256*8 = 2048 exactly

    const float* Wp = W + (size_t)c * FDIM + f0;
    float4 w0 = *(const float4*)Wp;
    float4 w1 = *(const float4*)(Wp + 4);
    float4 r0 = *(const float4*)(r + f0);
    float4 r1 = *(const float4*)(r + f0 + 4);
    r0.x = fmaxf(r0.x, EPS_R); r0.y = fmaxf(r0.y, EPS_R);
    r0.z = fmaxf(r0.z, EPS_R); r0.w = fmaxf(r0.w, EPS_R);
    r1.x = fmaxf(r1.x, EPS_R); r1.y = fmaxf(r1.y, EPS_R);
    r1.z = fmaxf(r1.z, EPS_R); r1.w = fmaxf(r1.w, EPS_R);

    if (c == 0) {
        *(float4*)(rc_out + f0) = r0;
        *(float4*)(rc_out + f0 + 4) = r1;
    }

    float rw0 = r0.x * w0.x, rw1 = r0.y * w0.y, rw2 = r0.z * w0.z, rw3 = r0.w * w0.w;
    float rw4 = r1.x * w1.x, rw5 = r1.y * w1.y, rw6 = r1.z * w1.z, rw7 = r1.w * w1.w;

    float part = rw0 * w0.x + rw1 * w0.y + rw2 * w0.z + rw3 * w0.w
               + rw4 * w1.x + rw5 * w1.y + rw6 * w1.z + rw7 * w1.w;

    unsigned h01, l01, h23, l23, h45, l45, h67, l67;
    split2(rw0 * WSCALE, rw1 * WSCALE, h01, l01);
    split2(rw2 * WSCALE, rw3 * WSCALE, h23, l23);
    split2(rw4 * WSCALE, rw5 * WSCALE, h45, l45);
    split2(rw6 * WSCALE, rw7 * WSCALE, h67, l67);

    // swizzled destination: chunk ch, class-row c, 16B slot for halves k6..k6+7
    const int ch = f0 >> 6;
    const int k6 = f0 & 63;
    const int rowoff = (k6 * 2) ^ ((c & 7) << 4);
    unsigned char* dst = Bsw + (size_t)ch * CHB + c * 128 + rowoff;
    *(uint4*)dst = make_uint4(h01, h23, h45, h67);          // bh region
    *(uint4*)(dst + 8192) = make_uint4(l01, l23, l45, l67); // bl region

#pragma unroll
    for (int m = 32; m; m >>= 1) part += __shfl_xor(part, m);
    __shared__ float red[4];
    if ((tid & 63) == 0) red[tid >> 6] = part;
    __syncthreads();
    if (tid == 0) wsq[c] = (red[0] + red[1]) + (red[2] + red[3]);
}

// ---- main: R1 structure + rc staged in LDS (VMEM 12->8 ops/lane/chunk) ----
__global__ __launch_bounds__(256, 2) void gmlvq_main(
    const float* __restrict__ X, const float* __restrict__ rc,
    const unsigned char* __restrict__ Bsw,
    const float* __restrict__ wsq_g,
    float* __restrict__ dists, float* __restrict__ preds) {

    __shared__ __align__(16) unsigned char lds_b[2][CHB];
    __shared__ __align__(16) float lds_rc[FDIM];    // 8 KiB, staged once
    __shared__ float lds_xsq[BM];
    __shared__ float lds_wsq[CDIM];

    const int tid  = threadIdx.x;
    const int wave = tid >> 6;
    const int lane = tid & 63;
    const int quad = lane >> 4;
    const int l15  = lane & 15;
    const int row_base = blockIdx.x * BM;
    const int wu = __builtin_amdgcn_readfirstlane(wave);   // uniform wave id

    if (tid < CDIM) lds_wsq[tid] = wsq_g[tid];

    const float* Ap = X + (size_t)(row_base + wave * 16 + l15) * FDIM + quad * 8;

    // swizzled column base for LDS fragment reads (bits 4-6); ks=1 is ^64
    const int col0 = ((quad ^ (l15 & 7)) << 4);

    // prologue: DMA chunk 0 -> buf0; DMA rc -> lds_rc; A chunk 0 -> regs
    {
        const unsigned char* src = Bsw + (size_t)wu * 4096 + lane * 16;
        unsigned char* dst = &lds_b[0][wu * 4096];
#pragma unroll
        for (int j = 0; j < 4; j++) async16(src + j * 1024, dst + j * 1024);

        const unsigned char* rsrc = (const unsigned char*)rc + wu * 1024 + lane * 16;
        unsigned char* rdst = (unsigned char*)lds_rc + wu * 1024;
        async16(rsrc, rdst);                 // 4 KiB across 4 waves
        async16(rsrc + 4096, rdst + 4096);   // second half
    }
    float4 x0 = *(const float4*)(Ap);
    float4 x1 = *(const float4*)(Ap + 4);
    float4 x2 = *(const float4*)(Ap + 32);
    float4 x3 = *(const float4*)(Ap + 36);

    float p = 0.f;     // per-lane x_sq partial
    f32x4 acc[4];
#pragma unroll
    for (int n = 0; n < 4; n++) acc[n] = (f32x4){0.f, 0.f, 0.f, 0.f};

#pragma unroll 2
    for (int c = 0; c < NCH; c++) {
        __syncthreads();            // buf[c&1] + (iter 0) lds_rc landed
        const int bb = c & 1;
        const int cn = (c + 1) & (NCH - 1);      // ring; wrap harmless

        // stage next B chunk into buf^1 (async DMA; lands by next barrier)
        {
            const unsigned char* src = Bsw + (size_t)cn * CHB + wu * 4096 + lane * 16;
            unsigned char* dst = &lds_b[bb ^ 1][wu * 4096];
#pragma unroll
            for (int j = 0; j < 4; j++) async16(src + j * 1024, dst + j * 1024);
        }

        // prefetch next A chunk into regs (X only; rc now lives in LDS)
        const int kn = cn * BK;
        const float4 xn0 = *(const float4*)(Ap + kn);
        const float4 xn1 = *(const float4*)(Ap + kn + 4);
        const float4 xn2 = *(const float4*)(Ap + kn + 32);
        const float4 xn3 = *(const float4*)(Ap + kn + 36);

        // rc slices for the CURRENT chunk from LDS (quad-broadcast, conflict-free)
        const float* rck = &lds_rc[c * BK + quad * 8];
        const float4 rc0 = *(const float4*)(rck);
        const float4 rc1 = *(const float4*)(rck + 4);
        const float4 rc2 = *(const float4*)(rck + 32);
        const float4 rc3 = *(const float4*)(rck + 36);

        // split current A regs into fp16 hi/lo frags + r*x^2 partial
        half8 ah0, al0, ah1, al1;
        split8(x0, x1, rc0, rc1, ah0, al0, p);   // k-slice 0 (halves 0..31)
        split8(x2, x3, rc2, rc3, ah1, al1, p);   // k-slice 1 (halves 32..63)

        const unsigned char* Lb = lds_b[bb];
#pragma unroll
        for (int n = 0; n < 4; n++) {
            const int o = ((n * 16 + l15) << 7) + col0;   // class-row * 128 + swz col
            const half8 bh0 = *(const half8*)(Lb + o);
            const half8 bh1 = *(const half8*)(Lb + (o ^ 64));
            const half8 bl0 = *(const half8*)(Lb + 8192 + o);
            const half8 bl1 = *(const half8*)(Lb + 8192 + (o ^ 64));
            acc[n] = __builtin_amdgcn_mfma_f32_16x16x32_f16(ah0, bh0, acc[n], 0, 0, 0);
            acc[n] = __builtin_amdgcn_mfma_f32_16x16x32_f16(ah0, bl0, acc[n], 0, 0, 0);
            acc[n] = __builtin_amdgcn_mfma_f32_16x16x32_f16(al0, bh0, acc[n], 0, 0, 0);
            acc[n] = __builtin_amdgcn_mfma_f32_16x16x32_f16(ah1, bh1, acc[n], 0, 0, 0);
            acc[n] = __builtin_amdgcn_mfma_f32_16x16x32_f16(ah1, bl1, acc[n], 0, 0, 0);
            acc[n] = __builtin_amdgcn_mfma_f32_16x16x32_f16(al1, bh1, acc[n], 0, 0, 0);
        }

        x0 = xn0; x1 = xn1; x2 = xn2; x3 = xn3;
    }

    // x_sq: reduce across the 4 quads holding the same row
    p += __shfl_xor(p, 16);
    p += __shfl_xor(p, 32);
    if (quad == 0) lds_xsq[wave * 16 + l15] = p;
    __syncthreads();

    // epilogue: d = x_sq + w_sq - 2*cross ; C/D layout: col=lane&15, row=quad*4+reg
    float dd[4][4];
#pragma unroll
    for (int n = 0; n < 4; n++) {
#pragma unroll
        for (int rr = 0; rr < 4; rr++) {
            const int m = wave * 16 + quad * 4 + rr;
            const int cc = n * 16 + l15;
            const float d = lds_xsq[m] + lds_wsq[cc] - acc[n][rr] * DESCALE;
            dd[n][rr] = d;
            dists[(size_t)(row_base + m) * CDIM + cc] = d;
        }
    }

    // argmin over 64 classes per row (lowest-index tie-break)
#pragma unroll
    for (int rr = 0; rr < 4; rr++) {
        float bv = dd[0][rr];
        int   bi = l15;
#pragma unroll
        for (int n = 1; n < 4; n++) {
            const float v = dd[n][rr];
            const int  ci = n * 16 + l15;
            if (v < bv || (v == bv && ci < bi)) { bv = v; bi = ci; }
        }
#pragma unroll
        for (int mask = 1; mask < 16; mask <<= 1) {
            const float ov = __shfl_xor(bv, mask);
            const int   oi = __shfl_xor(bi, mask);
            if (ov < bv || (ov == bv && oi < bi)) { bv = ov; bi = oi; }
        }
        if (l15 == 0) {
            const int m = wave * 16 + quad * 4 + rr;
            preds[row_base + m] = (float)bi;
        }
    }
}

extern "C" void kernel_launch(void* const* d_in, const int* in_sizes, int n_in,
                              void* d_out, int out_size, void* d_ws, size_t ws_size,
                              hipStream_t stream) {
    const float* X = (const float*)d_in[0];
    const float* W = (const float*)d_in[1];
    const float* r = (const float*)d_in[2];
    float* dists = (float*)d_out;
    float* preds = dists + (size_t)NROWS * CDIM;

    unsigned char* Bsw = (unsigned char*)d_ws;                  // 512 KiB swizzled B image
    float* wsq   = (float*)(Bsw + (size_t)NCH * CHB);           // 256 B
    float* rc_ws = wsq + CDIM;                                  // 8 KiB

    gmlvq_prep<<<dim3(CDIM), dim3(256), 0, stream>>>(W, r, Bsw, wsq, rc_ws);
    gmlvq_main<<<dim3(NROWS / BM), dim3(256), 0, stream>>>(X, rc_ws, Bsw, wsq, dists, preds);
}